// Round 4
// baseline (1668.820 us; speedup 1.0000x reference)
//
#include <hip/hip_runtime.h>
#include <hip/hip_bf16.h>

#define BBATCH 2
#define MMROWS 4096
#define NNB 32
#define DIMD 256
#define NHEADS 8
#define FFD 512
#define MT 16
#define LNEPS 1e-5f

typedef short bf16x8 __attribute__((ext_vector_type(8)));
typedef float f32x4 __attribute__((ext_vector_type(4)));

__device__ __forceinline__ unsigned short f2bf(float f) {
    union { float f; unsigned int u; } a; a.f = f;
    unsigned int u = a.u;
    unsigned int r = (u + 0x7fffu + ((u >> 16) & 1u)) >> 16;
    return (unsigned short)r;
}
__device__ __forceinline__ float bf2f(unsigned short h) {
    union { unsigned int u; float f; } a; a.u = ((unsigned int)h) << 16;
    return a.f;
}

// ws layout (bf16 elements):
//   Wq    native [256][256]      @ 0
//   WkT   transposed [d'][o]     @ 65536
//   Wv hi native [256][256]      @ 131072
//   Wp hi native [256][256]      @ 196608
//   W1    native [512][256]      @ 262144
//   W2    native [256][512]      @ 393216
//   Wp lo native [256][256]      @ 524288
__global__ void prep_weights(const float* __restrict__ Wq, const float* __restrict__ Wk,
                             const float* __restrict__ Wv, const float* __restrict__ Wp,
                             const float* __restrict__ W1, const float* __restrict__ W2,
                             unsigned short* __restrict__ ws) {
    int i = blockIdx.x * 256 + threadIdx.x;
    if (i < 65536)       { ws[i] = f2bf(Wq[i]); }
    else if (i < 131072) { int l = i - 65536; int dp = l >> 8, o = l & 255; ws[i] = f2bf(Wk[o * 256 + dp]); }
    else if (i < 196608) { ws[i] = f2bf(Wv[i - 131072]); }
    else if (i < 262144) { ws[i] = f2bf(Wp[i - 196608]); }
    else if (i < 393216) { ws[i] = f2bf(W1[i - 262144]); }
    else if (i < 524288) { ws[i] = f2bf(W2[i - 393216]); }
    else if (i < 589824) { float w = Wp[i - 524288]; ws[i] = f2bf(w - bf2f(f2bf(w))); }
}

__device__ __forceinline__ void rowstats(float4 v, float& mu, float& inv) {
    float s  = v.x + v.y + v.z + v.w;
    float ss = v.x * v.x + v.y * v.y + v.z * v.z + v.w * v.w;
    #pragma unroll
    for (int off = 32; off; off >>= 1) {
        s  += __shfl_xor(s, off);
        ss += __shfl_xor(ss, off);
    }
    mu  = s * (1.f / 256.f);
    float var = ss * (1.f / 256.f) - mu * mu;
    inv = rsqrtf(fmaxf(var, 0.f) + LNEPS);
}

__global__ __launch_bounds__(256, 2)
void fused_mhca(const float* __restrict__ x, const float* __restrict__ y,
                const float* __restrict__ lnq_w, const float* __restrict__ lnq_b,
                const float* __restrict__ bq,
                const float* __restrict__ lnk_w,
                const float* __restrict__ lnv_w, const float* __restrict__ lnv_b,
                const float* __restrict__ bv,
                const float* __restrict__ bp,
                const float* __restrict__ pre_w, const float* __restrict__ pre_b,
                const float* __restrict__ b1, const float* __restrict__ b2,
                const float* __restrict__ post_w, const float* __restrict__ post_b,
                const unsigned short* __restrict__ wsb,
                float* __restrict__ out) {
    const int tid  = threadIdx.x;
    const int lane = tid & 63;
    const int wid  = tid >> 6;        // wave 0..3
    const int q4   = lane >> 4;       // quad 0..3
    const int l16  = lane & 15;
    const int b    = blockIdx.x >> 8;         // 256 m-tiles per batch
    const int m0   = (blockIdx.x & 255) * MT;
    const float scale = 0.17677669529663687f; // 1/sqrt(32)

    const unsigned short* Wq_bf   = wsb;
    const unsigned short* WkT_bf  = wsb + 65536;
    const unsigned short* Wv_bf   = wsb + 131072;
    const unsigned short* Wp_bf   = wsb + 196608;
    const unsigned short* W1_bf   = wsb + 262144;
    const unsigned short* W2_bf   = wsb + 393216;
    const unsigned short* Wplo_bf = wsb + 524288;

    __shared__ __align__(16) union UU {
        unsigned short lnX[MT][264];                       // P1/P2
        unsigned short Y[2][NNB][264];                     // P3: normalized y (no affine)
        struct { float Z[MT][260]; unsigned short G[MT][520]; } p4;  // P4
    } big;
    __shared__ __align__(16) unsigned short sQ[MT][264];   // q' scaled (P2->P3), then lnZ (P4)
    __shared__ __align__(16) float sTUf[2][NHEADS][260];   // t' then u (fp32), per slot
    __shared__ __align__(16) float sL[2][NNB][8];          // logits then probs (fp32)
    __shared__ __align__(16) float sAf[MT][260];           // attention output (fp32)

    // ---------------- P1: layernorm(x) -> big.lnX (bf16, with lnq affine) ----
    {
        const float4 w4 = *(const float4*)(lnq_w + lane * 4);
        const float4 g4 = *(const float4*)(lnq_b + lane * 4);
        float4 xv[4];
        #pragma unroll
        for (int rr = 0; rr < 4; rr++) {
            int m = wid * 4 + rr;
            xv[rr] = *(const float4*)(x + (size_t)(b * MMROWS + m0 + m) * DIMD + lane * 4);
        }
        #pragma unroll
        for (int rr = 0; rr < 4; rr++) {
            int m = wid * 4 + rr;
            float mu, inv; rowstats(xv[rr], mu, inv);
            float4 v = xv[rr];
            ushort4 o;
            o.x = f2bf((v.x - mu) * inv * w4.x + g4.x);
            o.y = f2bf((v.y - mu) * inv * w4.y + g4.y);
            o.z = f2bf((v.z - mu) * inv * w4.z + g4.z);
            o.w = f2bf((v.w - mu) * inv * w4.w + g4.w);
            *(ushort4*)&big.lnX[m][lane * 4] = o;
        }
    }
    __syncthreads();

    // ---------------- P2: q' = (lnX @ Wq^T + bq) * scale -> sQ (bf16) --------
    {
        f32x4 acc[4];
        #pragma unroll
        for (int j = 0; j < 4; j++) acc[j] = 0.f;
        #pragma unroll
        for (int k = 0; k < 8; k++) {
            bf16x8 af = *(const bf16x8*)&big.lnX[l16][k * 32 + q4 * 8];
            #pragma unroll
            for (int j = 0; j < 4; j++) {
                int o = wid * 64 + j * 16 + l16;
                bf16x8 bfv = *(const bf16x8*)(Wq_bf + o * DIMD + k * 32 + q4 * 8);
                acc[j] = __builtin_amdgcn_mfma_f32_16x16x32_bf16(af, bfv, acc[j], 0, 0, 0);
            }
        }
        #pragma unroll
        for (int j = 0; j < 4; j++) {
            int o = wid * 64 + j * 16 + l16;
            float bqv = bq[o];
            #pragma unroll
            for (int r = 0; r < 4; r++) {
                sQ[q4 * 4 + r][o] = f2bf((acc[j][r] + bqv) * scale);
            }
        }
    }
    __syncthreads();

    // ---------------- P3: attention (fp32 VALU core), 2 m-rows per subgroup --
    const int slot = wid >> 1;   // which m of the pair this wave serves
    const int wp   = wid & 1;    // wave-in-pair
    for (int sg = 0; sg < 8; sg++) {
        const int mg = m0 + sg * 2;

        // --- LN(y) -> big.Y[slot] (bf16, pure normalize, no affine) ---
        {
            for (int rc = 0; rc < 16; rc += 4) {
                float4 vv[4];
                #pragma unroll
                for (int u = 0; u < 4; u++) {
                    int n = wp * 16 + rc + u;
                    vv[u] = *(const float4*)(y + ((size_t)((b * MMROWS + mg + slot) * NNB + n)) * DIMD + lane * 4);
                }
                #pragma unroll
                for (int u = 0; u < 4; u++) {
                    int n = wp * 16 + rc + u;
                    float mu, inv; rowstats(vv[u], mu, inv);
                    float4 v = vv[u];
                    ushort4 o;
                    o.x = f2bf((v.x - mu) * inv);
                    o.y = f2bf((v.y - mu) * inv);
                    o.z = f2bf((v.z - mu) * inv);
                    o.w = f2bf((v.w - mu) * inv);
                    *(ushort4*)&big.Y[slot][n][lane * 4] = o;
                }
            }
        }

        // --- t'[h][dp] = (Wk_h^T q'_h)[dp] * lnk_w[dp]  (fp32 VALU) ---
        // wave (slot,wp) computes heads h = wp*4 .. wp*4+3 of its slot, all 256 dp.
        {
            const int row = sg * 2 + slot;
            float acc[4][4]; // [dpk][hh]
            #pragma unroll
            for (int a = 0; a < 4; a++)
                #pragma unroll
                for (int c = 0; c < 4; c++) acc[a][c] = 0.f;
            #pragma unroll
            for (int hh = 0; hh < 4; hh++) {
                const int h = wp * 4 + hh;
                float qv[32];
                #pragma unroll
                for (int dv = 0; dv < 4; dv++) {
                    bf16x8 q8 = *(const bf16x8*)&sQ[row][h * 32 + dv * 8];
                    #pragma unroll
                    for (int j = 0; j < 8; j++) qv[dv * 8 + j] = bf2f((unsigned short)q8[j]);
                }
                #pragma unroll
                for (int dpk = 0; dpk < 4; dpk++) {
                    const int dp = lane + dpk * 64;
                    #pragma unroll
                    for (int dv = 0; dv < 4; dv++) {
                        bf16x8 wk8 = *(const bf16x8*)(WkT_bf + dp * 256 + h * 32 + dv * 8);
                        #pragma unroll
                        for (int j = 0; j < 8; j++)
                            acc[dpk][hh] += qv[dv * 8 + j] * bf2f((unsigned short)wk8[j]);
                    }
                }
            }
            #pragma unroll
            for (int dpk = 0; dpk < 4; dpk++) {
                const int dp = lane + dpk * 64;
                const float wkw = lnk_w[dp];
                #pragma unroll
                for (int hh = 0; hh < 4; hh++)
                    sTUf[slot][wp * 4 + hh][dp] = acc[dpk][hh] * wkw;
            }
        }
        __syncthreads();

        // --- logits[n][h] = Y[n] . t'[h]  (fp32 VALU; scale already in q') ---
        // lane -> (n = wp*16 + (lane>>3) + pass*8, h = lane&7)
        #pragma unroll
        for (int pass = 0; pass < 2; pass++) {
            const int n = wp * 16 + (lane >> 3) + pass * 8;
            const int h = lane & 7;
            float accl = 0.f;
            #pragma unroll 8
            for (int dv = 0; dv < 32; dv++) {
                bf16x8 y8 = *(const bf16x8*)&big.Y[slot][n][dv * 8];
                float4 ta = *(const float4*)&sTUf[slot][h][dv * 8];
                float4 tb = *(const float4*)&sTUf[slot][h][dv * 8 + 4];
                accl += bf2f((unsigned short)y8[0]) * ta.x;
                accl += bf2f((unsigned short)y8[1]) * ta.y;
                accl += bf2f((unsigned short)y8[2]) * ta.z;
                accl += bf2f((unsigned short)y8[3]) * ta.w;
                accl += bf2f((unsigned short)y8[4]) * tb.x;
                accl += bf2f((unsigned short)y8[5]) * tb.y;
                accl += bf2f((unsigned short)y8[6]) * tb.z;
                accl += bf2f((unsigned short)y8[7]) * tb.w;
            }
            sL[slot][n][h] = accl;
        }
        __syncthreads();

        // --- softmax over n (fp32, in place), done by the wp==0 wave ---
        if (wp == 0) {
            const int h = lane >> 3, i = lane & 7;
            float v0 = sL[slot][i][h],      v1 = sL[slot][i + 8][h];
            float v2 = sL[slot][i + 16][h], v3 = sL[slot][i + 24][h];
            float mx = fmaxf(fmaxf(v0, v1), fmaxf(v2, v3));
            mx = fmaxf(mx, __shfl_xor(mx, 1));
            mx = fmaxf(mx, __shfl_xor(mx, 2));
            mx = fmaxf(mx, __shfl_xor(mx, 4));
            float e0 = __expf(v0 - mx), e1 = __expf(v1 - mx);
            float e2 = __expf(v2 - mx), e3 = __expf(v3 - mx);
            float s = e0 + e1 + e2 + e3;
            s += __shfl_xor(s, 1);
            s += __shfl_xor(s, 2);
            s += __shfl_xor(s, 4);
            float r = 1.f / s;
            sL[slot][i][h]      = e0 * r;
            sL[slot][i + 8][h]  = e1 * r;
            sL[slot][i + 16][h] = e2 * r;
            sL[slot][i + 24][h] = e3 * r;
        }
        __syncthreads();

        // --- u[h][dp] = lnv_w[dp]*(sum_n p[n][h] Y[n][dp]) + lnv_b[dp] ---
        // lane -> dp pair {wp*128+2*lane, +1}; overwrites t' (consumed above).
        {
            const int dp0 = wp * 128 + lane * 2, dp1 = dp0 + 1;
            float acc0[8], acc1[8];
            #pragma unroll
            for (int h = 0; h < 8; h++) { acc0[h] = 0.f; acc1[h] = 0.f; }
            #pragma unroll 8
            for (int n = 0; n < 32; n++) {
                float y0 = bf2f(big.Y[slot][n][dp0]);
                float y1 = bf2f(big.Y[slot][n][dp1]);
                float4 pA = *(const float4*)&sL[slot][n][0];
                float4 pB = *(const float4*)&sL[slot][n][4];
                acc0[0] += pA.x * y0; acc1[0] += pA.x * y1;
                acc0[1] += pA.y * y0; acc1[1] += pA.y * y1;
                acc0[2] += pA.z * y0; acc1[2] += pA.z * y1;
                acc0[3] += pA.w * y0; acc1[3] += pA.w * y1;
                acc0[4] += pB.x * y0; acc1[4] += pB.x * y1;
                acc0[5] += pB.y * y0; acc1[5] += pB.y * y1;
                acc0[6] += pB.z * y0; acc1[6] += pB.z * y1;
                acc0[7] += pB.w * y0; acc1[7] += pB.w * y1;
            }
            const float w0 = lnv_w[dp0], g0 = lnv_b[dp0];
            const float w1 = lnv_w[dp1], g1 = lnv_b[dp1];
            #pragma unroll
            for (int h = 0; h < 8; h++) {
                sTUf[slot][h][dp0] = acc0[h] * w0 + g0;
                sTUf[slot][h][dp1] = acc1[h] * w1 + g1;
            }
        }
        __syncthreads();

        // --- a[o] = sum_dp u[h(o)][dp] * Wv[o][dp] + bv[o]  (fp32 VALU) ---
        {
            #pragma unroll
            for (int oo = 0; oo < 2; oo++) {
                const int o = wp * 128 + lane * 2 + oo;
                const int h = o >> 5;
                float acc = 0.f;
                #pragma unroll 8
                for (int dpv = 0; dpv < 32; dpv++) {
                    bf16x8 wv8 = *(const bf16x8*)(Wv_bf + o * 256 + dpv * 8);
                    float4 ua = *(const float4*)&sTUf[slot][h][dpv * 8];
                    float4 ub = *(const float4*)&sTUf[slot][h][dpv * 8 + 4];
                    acc += bf2f((unsigned short)wv8[0]) * ua.x;
                    acc += bf2f((unsigned short)wv8[1]) * ua.y;
                    acc += bf2f((unsigned short)wv8[2]) * ua.z;
                    acc += bf2f((unsigned short)wv8[3]) * ua.w;
                    acc += bf2f((unsigned short)wv8[4]) * ub.x;
                    acc += bf2f((unsigned short)wv8[5]) * ub.y;
                    acc += bf2f((unsigned short)wv8[6]) * ub.z;
                    acc += bf2f((unsigned short)wv8[7]) * ub.w;
                }
                sAf[sg * 2 + slot][o] = acc + bv[o];
            }
        }
        __syncthreads();
    }

    // ---------------- P4: z-proj, LN, FFN, residual, final LN ----------------
    // z = sAf @ Wp^T + bp -> big.p4.Z (fp32); A split hi/lo on the fly, Wp hi/lo.
    {
        f32x4 acc[4];
        #pragma unroll
        for (int j = 0; j < 4; j++) acc[j] = 0.f;
        #pragma unroll
        for (int k = 0; k < 8; k++) {
            float4 va = *(const float4*)&sAf[l16][k * 32 + q4 * 8];
            float4 vb = *(const float4*)&sAf[l16][k * 32 + q4 * 8 + 4];
            float vs[8] = {va.x, va.y, va.z, va.w, vb.x, vb.y, vb.z, vb.w};
            bf16x8 ah, al;
            #pragma unroll
            for (int j = 0; j < 8; j++) {
                unsigned short hi = f2bf(vs[j]);
                ah[j] = (short)hi;
                al[j] = (short)f2bf(vs[j] - bf2f(hi));
            }
            #pragma unroll
            for (int j = 0; j < 4; j++) {
                int o = wid * 64 + j * 16 + l16;
                bf16x8 bh = *(const bf16x8*)(Wp_bf   + o * DIMD + k * 32 + q4 * 8);
                bf16x8 bl = *(const bf16x8*)(Wplo_bf + o * DIMD + k * 32 + q4 * 8);
                acc[j] = __builtin_amdgcn_mfma_f32_16x16x32_bf16(ah, bh, acc[j], 0, 0, 0);
                acc[j] = __builtin_amdgcn_mfma_f32_16x16x32_bf16(al, bh, acc[j], 0, 0, 0);
                acc[j] = __builtin_amdgcn_mfma_f32_16x16x32_bf16(ah, bl, acc[j], 0, 0, 0);
            }
        }
        #pragma unroll
        for (int j = 0; j < 4; j++) {
            int o = wid * 64 + j * 16 + l16;
            float bpv = bp[o];
            #pragma unroll
            for (int r = 0; r < 4; r++) big.p4.Z[q4 * 4 + r][o] = acc[j][r] + bpv;
        }
    }
    __syncthreads();
    // lnZ: normalize Z in place (fp32, residual base) AND stash bf16 copy in sQ
    {
        const float4 w4 = *(const float4*)(pre_w + lane * 4);
        const float4 g4 = *(const float4*)(pre_b + lane * 4);
        #pragma unroll
        for (int rr = 0; rr < 4; rr++) {
            int m = wid * 4 + rr;
            float4 v = *(const float4*)&big.p4.Z[m][lane * 4];
            float mu, inv; rowstats(v, mu, inv);
            float4 z;
            z.x = (v.x - mu) * inv * w4.x + g4.x;
            z.y = (v.y - mu) * inv * w4.y + g4.y;
            z.z = (v.z - mu) * inv * w4.z + g4.z;
            z.w = (v.w - mu) * inv * w4.w + g4.w;
            *(float4*)&big.p4.Z[m][lane * 4] = z;   // residual base = ln(z)
            ushort4 o;
            o.x = f2bf(z.x); o.y = f2bf(z.y); o.z = f2bf(z.z); o.w = f2bf(z.w);
            *(ushort4*)&sQ[m][lane * 4] = o;
        }
    }
    __syncthreads();
    // FFN1 + exact gelu -> big.p4.G
    {
        f32x4 acc[8];
        #pragma unroll
        for (int j = 0; j < 8; j++) acc[j] = 0.f;
        #pragma unroll
        for (int k = 0; k < 8; k++) {
            bf16x8 af = *(const bf16x8*)&sQ[l16][k * 32 + q4 * 8];
            #pragma unroll
            for (int j = 0; j < 8; j++) {
                int f = wid * 128 + j * 16 + l16;
                bf16x8 bfv = *(const bf16x8*)(W1_bf + f * DIMD + k * 32 + q4 * 8);
                acc[j] = __builtin_amdgcn_mfma_f32_16x16x32_bf16(af, bfv, acc[j], 0, 0, 0);
            }
        }
        #pragma unroll
        for (int j = 0; j < 8; j++) {
            int f = wid * 128 + j * 16 + l16;
            float b1v = b1[f];
            #pragma unroll
            for (int r = 0; r < 4; r++) {
                float vz = acc[j][r] + b1v;
                float g = 0.5f * vz * (1.f + erff(vz * 0.7071067811865475f));
                big.p4.G[q4 * 4 + r][f] = f2bf(g);
            }
        }
    }
    __syncthreads();
    // FFN2 + residual -> Z (in place; Z holds ln(z))
    {
        f32x4 acc[4];
        #pragma unroll
        for (int j = 0; j < 4; j++) acc[j] = 0.f;
        #pragma unroll
        for (int k = 0; k < 16; k++) {
            bf16x8 af = *(const bf16x8*)&big.p4.G[l16][k * 32 + q4 * 8];
            #pragma unroll
            for (int j = 0; j < 4; j++) {
                int o = wid * 64 + j * 16 + l16;
                bf16x8 bfv = *(const bf16x8*)(W2_bf + o * FFD + k * 32 + q4 * 8);
                acc[j] = __builtin_amdgcn_mfma_f32_16x16x32_bf16(af, bfv, acc[j], 0, 0, 0);
            }
        }
        #pragma unroll
        for (int j = 0; j < 4; j++) {
            int o = wid * 64 + j * 16 + l16;
            float b2v = b2[o];
            #pragma unroll
            for (int r = 0; r < 4; r++) {
                big.p4.Z[q4 * 4 + r][o] += acc[j][r] + b2v;
            }
        }
    }
    __syncthreads();
    // final LN -> out
    {
        const float4 w4 = *(const float4*)(post_w + lane * 4);
        const float4 g4 = *(const float4*)(post_b + lane * 4);
        #pragma unroll
        for (int rr = 0; rr < 4; rr++) {
            int m = wid * 4 + rr;
            float4 v = *(const float4*)&big.p4.Z[m][lane * 4];
            float mu, inv; rowstats(v, mu, inv);
            float4 o;
            o.x = (v.x - mu) * inv * w4.x + g4.x;
            o.y = (v.y - mu) * inv * w4.y + g4.y;
            o.z = (v.z - mu) * inv * w4.z + g4.z;
            o.w = (v.w - mu) * inv * w4.w + g4.w;
            *(float4*)(out + (size_t)(b * MMROWS + m0 + m) * DIMD + lane * 4) = o;
        }
    }
}

extern "C" void kernel_launch(void* const* d_in, const int* in_sizes, int n_in,
                              void* d_out, int out_size, void* d_ws, size_t ws_size,
                              hipStream_t stream) {
    (void)in_sizes; (void)n_in; (void)out_size; (void)ws_size;
    const float* x      = (const float*)d_in[0];
    const float* y      = (const float*)d_in[1];
    const float* lnq_w  = (const float*)d_in[2];
    const float* lnq_b  = (const float*)d_in[3];
    const float* Wq     = (const float*)d_in[4];
    const float* bq     = (const float*)d_in[5];
    const float* lnk_w  = (const float*)d_in[6];
    // d_in[7] = lnk_b : softmax-invariant (dropped)
    const float* Wk     = (const float*)d_in[8];
    // d_in[9] = bk : softmax-invariant (dropped)
    const float* lnv_w  = (const float*)d_in[10];
    const float* lnv_b  = (const float*)d_in[11];
    const float* Wv     = (const float*)d_in[12];
    const float* bv     = (const float*)d_in[13];
    const float* Wp     = (const float*)d_in[14];
    const float* bp     = (const float*)d_in[15];
    const float* pre_w  = (const float*)d_in[16];
    const float* pre_b  = (const float*)d_in[17];
    const float* W1     = (const float*)d_in[18];
    const float* b1     = (const float*)d_in[19];
    const float* W2     = (const float*)d_in[20];
    const float* b2     = (const float*)d_in[21];
    const float* post_w = (const float*)d_in[22];
    const float* post_b = (const float*)d_in[23];
    unsigned short* wsb = (unsigned short*)d_ws;

    prep_weights<<<2304, 256, 0, stream>>>(Wq, Wk, Wv, Wp, W1, W2, wsb);
    fused_mhca<<<512, 256, 0, stream>>>(x, y, lnq_w, lnq_b, bq, lnk_w,
                                        lnv_w, lnv_b, bv, bp, pre_w, pre_b,
                                        b1, b2, post_w, post_b, wsb, (float*)d_out);
}